// Round 8
// baseline (373.021 us; speedup 1.0000x reference)
//
#include <hip/hip_runtime.h>
#include <math.h>

#define NB 4
#define NS 2048
#define HD 768
#define ID 3072
#define NE 8
#define NTOK (NB*NS)      // 8192
#define NPAIR (NTOK*2)    // 16384

// ---- fast path tiling ----
#define BMF 128
#define BNF 256
#define BN2 128
#define BKF 64
#define MAXTF 136                 // max tiles: 128 full + 8 partial

// ---- fallback tiling ----
#define BMS 32
#define KCH 128
#define NCHUNK (ID/KCH)
#define MAXTS (NPAIR/BMS + NE)   // 520
#define LDP 36

typedef unsigned short u16;
typedef __attribute__((ext_vector_type(8))) short bf16x8;
typedef __attribute__((ext_vector_type(4))) float f32x4;

__device__ __forceinline__ float bf2f(u16 u) {
  union { unsigned int i; float f; } v; v.i = ((unsigned int)u) << 16; return v.f;
}
__device__ __forceinline__ u16 f2bf(float f) {
  union { float fl; unsigned int i; } v; v.fl = f;
  unsigned int r = v.i + 0x7fffu + ((v.i >> 16) & 1u);   // RNE
  return (u16)(r >> 16);
}
__device__ __forceinline__ void gload16(const void* g, void* l) {
  __builtin_amdgcn_global_load_lds(
      (const __attribute__((address_space(1))) void*)g,
      (__attribute__((address_space(3))) void*)l, 16, 0, 0);
}
__device__ __forceinline__ float gelu_fast(float x) {
  float u = 0.7978845608028654f * (x + 0.044715f * x * x * x);
  float e = __expf(2.f * u);
  float t = 1.f - 2.f / (e + 1.f);
  return 0.5f * x * (1.f + t);
}
// bijective XCD-chunk swizzle over a 2D grid (m204 variant)
__device__ __forceinline__ int xcd_swz_2d() {
  int nwg  = gridDim.x * gridDim.y;
  int orig = blockIdx.x + blockIdx.y * gridDim.x;
  int q = nwg >> 3, r = nwg & 7;
  int xcd = orig & 7, i = orig >> 3;
  return (xcd < r) ? (xcd * (q + 1) + i) : (r * (q + 1) + (xcd - r) * q + i);
}

// ---------------- router: 1 wave per token, NO atomics ----------------
__global__ __launch_bounds__(256) void router_kernel(
    const float* __restrict__ x, const float* __restrict__ rw,
    const float* __restrict__ rb, float* __restrict__ gating,
    int* __restrict__ topi, float* __restrict__ topw)
{
  int wid = threadIdx.x >> 6, lane = threadIdx.x & 63;
  int tok = blockIdx.x * 4 + wid;
  float acc[NE];
  #pragma unroll
  for (int e = 0; e < NE; ++e) acc[e] = 0.f;
  const float* xr = x + (size_t)tok * HD;
  #pragma unroll
  for (int r = 0; r < 3; ++r) {
    int h4 = (r*64 + lane) * 4;
    float4 xv = *(const float4*)&xr[h4];
    const float4* wr = (const float4*)(rw + (size_t)h4 * NE);
    float4 a0 = wr[0], c0 = wr[1], a1 = wr[2], c1 = wr[3];
    float4 a2 = wr[4], c2 = wr[5], a3 = wr[6], c3 = wr[7];
    acc[0] += xv.x*a0.x + xv.y*a1.x + xv.z*a2.x + xv.w*a3.x;
    acc[1] += xv.x*a0.y + xv.y*a1.y + xv.z*a2.y + xv.w*a3.y;
    acc[2] += xv.x*a0.z + xv.y*a1.z + xv.z*a2.z + xv.w*a3.z;
    acc[3] += xv.x*a0.w + xv.y*a1.w + xv.z*a2.w + xv.w*a3.w;
    acc[4] += xv.x*c0.x + xv.y*c1.x + xv.z*c2.x + xv.w*c3.x;
    acc[5] += xv.x*c0.y + xv.y*c1.y + xv.z*c2.y + xv.w*c3.y;
    acc[6] += xv.x*c0.z + xv.y*c1.z + xv.z*c2.z + xv.w*c3.z;
    acc[7] += xv.x*c0.w + xv.y*c1.w + xv.z*c2.w + xv.w*c3.w;
  }
  #pragma unroll
  for (int off = 1; off < 64; off <<= 1) {
    #pragma unroll
    for (int e = 0; e < NE; ++e) acc[e] += __shfl_xor(acc[e], off);
  }
  float lg[NE];
  #pragma unroll
  for (int e = 0; e < NE; ++e) lg[e] = acc[e] + rb[e];
  int i0 = 0;
  #pragma unroll
  for (int e = 1; e < NE; ++e) if (lg[e] > lg[i0]) i0 = e;
  int i1 = (i0 == 0) ? 1 : 0;
  #pragma unroll
  for (int e = 0; e < NE; ++e) if (e != i0 && lg[e] > lg[i1]) i1 = e;
  float ex = expf(lg[i1] - lg[i0]);
  float s = 1.f + ex;
  float w0 = 1.f / s, w1v = ex / s;
  if (lane < NE)
    gating[(size_t)tok*NE + lane] = (lane==i0) ? w0 : (lane==i1 ? w1v : 0.f);
  if (lane == 0) {
    topi[2*tok] = i0; topi[2*tok+1] = i1;
    topw[2*tok] = w0; topw[2*tok+1] = w1v;
  }
}

// ---------- plan: counts + offsets + deterministic scatter + aux loss ----------
__global__ __launch_bounds__(1024) void plan_kernel(
    const int* __restrict__ topi, const float* __restrict__ topw,
    int* __restrict__ offs, int* __restrict__ tilesc,
    int* __restrict__ ptok, float* __restrict__ pwv, int bm,
    float* __restrict__ aux)
{
  __shared__ int   wcnt[16][NE];
  __shared__ int   wbase[16][NE];
  __shared__ float wsum[16][NE];
  int tid = threadIdx.x, w = tid >> 6, lane = tid & 63;
  int base = w * 1024;

  int cnt[NE];
  #pragma unroll
  for (int e = 0; e < NE; ++e) cnt[e] = 0;
  #pragma unroll
  for (int it = 0; it < 16; ++it) {
    int ti = topi[base + it*64 + lane];
    #pragma unroll
    for (int e = 0; e < NE; ++e) {
      unsigned long long m = __ballot(ti == e);
      cnt[e] += __popcll(m);
    }
  }
  if (lane == 0)
    #pragma unroll
    for (int e = 0; e < NE; ++e) wcnt[w][e] = cnt[e];
  __syncthreads();

  if (tid == 0) {
    int o = 0, tt = 0;
    for (int e = 0; e < NE; ++e) {
      offs[e] = o; tilesc[e] = tt;
      int run = o, tot = 0;
      for (int ww = 0; ww < 16; ++ww) { wbase[ww][e] = run; run += wcnt[ww][e]; tot += wcnt[ww][e]; }
      o += tot;
      tt += (tot + bm - 1) / bm;
    }
    offs[NE] = o; tilesc[NE] = tt;
  }
  __syncthreads();

  int run[NE];
  float lsum[NE];
  #pragma unroll
  for (int e = 0; e < NE; ++e) { run[e] = wbase[w][e]; lsum[e] = 0.f; }
  unsigned long long lt = (1ull << lane) - 1ull;
  #pragma unroll
  for (int it = 0; it < 16; ++it) {
    int p = base + it*64 + lane;
    int ti = topi[p];
    float tw = topw[p];
    int idx = 0;
    #pragma unroll
    for (int e = 0; e < NE; ++e) {
      unsigned long long m = __ballot(ti == e);
      int r = run[e] + __popcll(m & lt);
      if (ti == e) idx = r;
      run[e] += __popcll(m);
      lsum[e] += (ti == e) ? tw : 0.f;
    }
    ptok[idx] = p >> 1;
    pwv[idx] = tw;
  }
  #pragma unroll
  for (int off = 1; off < 64; off <<= 1) {
    #pragma unroll
    for (int e = 0; e < NE; ++e) lsum[e] += __shfl_xor(lsum[e], off);
  }
  if (lane == 0)
    #pragma unroll
    for (int e = 0; e < NE; ++e) wsum[w][e] = lsum[e];
  __syncthreads();
  if (tid == 0) {
    float imp[NE];
    for (int e = 0; e < NE; ++e) {
      float s = 0.f;
      for (int ww = 0; ww < 16; ++ww) s += wsum[ww][e];
      imp[e] = s;
    }
    float mean = 0.f;
    for (int e = 0; e < NE; ++e) mean += imp[e];
    mean *= (1.f/NE);
    float var = 0.f;
    for (int e = 0; e < NE; ++e) { float d = imp[e] - mean; var += d*d; }
    var *= (1.f/(NE-1));                       // ddof=1
    aux[0] = 0.01f * var / (mean*mean + 1e-8f);
  }
}

// ---------------- x f32 -> bf16 ----------------
__global__ __launch_bounds__(256) void cvt_x_kernel(
    const float* __restrict__ x, u16* __restrict__ xb)
{
  int i = (blockIdx.x * 256 + threadIdx.x) * 8;
  float4 a = *(const float4*)&x[i];
  float4 b = *(const float4*)&x[i + 4];
  uint4 o;
  o.x = (unsigned)f2bf(a.x) | ((unsigned)f2bf(a.y) << 16);
  o.y = (unsigned)f2bf(a.z) | ((unsigned)f2bf(a.w) << 16);
  o.z = (unsigned)f2bf(b.x) | ((unsigned)f2bf(b.y) << 16);
  o.w = (unsigned)f2bf(b.z) | ((unsigned)f2bf(b.w) << 16);
  *(uint4*)&xb[i] = o;
}

// ---------------- per-expert transpose f32[R][C] -> bf16[C][R] ----------------
__global__ __launch_bounds__(256) void transpose_bf16_kernel(
    const float* __restrict__ src, u16* __restrict__ dst, int R, int C)
{
  __shared__ u16 tile[64][65];
  int e = blockIdx.z;
  const float* s = src + (size_t)e * R * C;
  u16* d = dst + (size_t)e * R * C;
  int c0 = blockIdx.x * 64, r0 = blockIdx.y * 64;
  int t = threadIdx.x;
  int rr = t >> 4, c4 = (t & 15) * 4;
  #pragma unroll
  for (int rep = 0; rep < 4; ++rep) {
    int r = rr + rep * 16;
    float4 v = *(const float4*)&s[(size_t)(r0 + r) * C + c0 + c4];
    tile[r][c4+0] = f2bf(v.x); tile[r][c4+1] = f2bf(v.y);
    tile[r][c4+2] = f2bf(v.z); tile[r][c4+3] = f2bf(v.w);
  }
  __syncthreads();
  #pragma unroll
  for (int rep = 0; rep < 4; ++rep) {
    int w = t + rep * 256;
    int c = w >> 4, rq = (w & 15) * 4;
    ushort4 o;
    o.x = tile[rq+0][c]; o.y = tile[rq+1][c];
    o.z = tile[rq+2][c]; o.w = tile[rq+3][c];
    *(ushort4*)&d[(size_t)(c0 + c) * R + r0 + rq] = o;
  }
}

// ------- GEMM1: h = gelu(X @ w1 + b1) * gate   (bf16 MFMA, round-4 structure) -------
__global__ __launch_bounds__(512, 2) void moe_gemm1_kernel(
    const u16* __restrict__ xbf, const u16* __restrict__ w1t,
    const float* __restrict__ b1, const int* __restrict__ offs,
    const int* __restrict__ tilesc, const int* __restrict__ ptok,
    const float* __restrict__ pwv, u16* __restrict__ hbuf, int t0)
{
  __shared__ __align__(16) u16 As[BMF*BKF];   // 16 KB, src-swizzled
  __shared__ __align__(16) u16 Bs[BNF*BKF];   // 32 KB, src-swizzled
  __shared__ int   toks_s[BMF];
  __shared__ float gws_s[BMF];

  int wkid = xcd_swz_2d();
  int tile = wkid % gridDim.x;        // tile fastest: same-n0 neighbors on one XCD
  int n0   = (wkid / gridDim.x) * BNF;

  int t = t0 + tile;
  if (t >= tilesc[NE]) return;
  int e = 0;
  #pragma unroll
  for (int k = 1; k < NE; ++k) if (t >= tilesc[k]) e = k;
  int row0 = offs[e] + (t - tilesc[e]) * BMF;
  int nrows = offs[e+1] - row0; if (nrows > BMF) nrows = BMF;
  int tid = threadIdx.x, wid = tid >> 6, lane = tid & 63;

  if (tid < BMF) {
    int tk = -1; float g = 0.f;
    if (tid < nrows) { tk = ptok[row0 + tid]; g = pwv[row0 + tid]; }
    toks_s[tid] = tk; gws_s[tid] = g;
  }
  __syncthreads();

  int ssub = tid >> 3;
  int sbc  = (tid & 7) << 4;
  int swz  = sbc ^ ((ssub & 7) << 4);
  int tkA0 = toks_s[ssub];      if (tkA0 < 0) tkA0 = 0;
  int tkA1 = toks_s[64 + ssub]; if (tkA1 < 0) tkA1 = 0;
  const char* aS0 = (const char*)xbf + (size_t)tkA0 * (HD*2) + swz;
  const char* aS1 = (const char*)xbf + (size_t)tkA1 * (HD*2) + swz;
  const char* bS0 = (const char*)w1t + ((size_t)e*ID + n0 +       ssub) * (HD*2) + swz;
  const char* bS1 = (const char*)w1t + ((size_t)e*ID + n0 +  64 + ssub) * (HD*2) + swz;
  const char* bS2 = (const char*)w1t + ((size_t)e*ID + n0 + 128 + ssub) * (HD*2) + swz;
  const char* bS3 = (const char*)w1t + ((size_t)e*ID + n0 + 192 + ssub) * (HD*2) + swz;
  u16* aD0 = As + wid*512;
  u16* aD1 = As + 4096 + wid*512;
  u16* bD0 = Bs + wid*512;
  u16* bD1 = Bs +  4096 + wid*512;
  u16* bD2 = Bs +  8192 + wid*512;
  u16* bD3 = Bs + 12288 + wid*512;

  int wr = wid >> 2, wc = wid & 3;      // 2 x 4 wave grid, 64x64 per wave
  int lr = lane & 15, lg = lane >> 4;

  f32x4 acc[4][4];
  #pragma unroll
  for (int m = 0; m < 4; ++m)
    #pragma unroll
    for (int n = 0; n < 4; ++n) { f32x4 z = {0.f,0.f,0.f,0.f}; acc[m][n] = z; }

  for (int ks = 0; ks < HD/BKF; ++ks) {   // 12
    __syncthreads();
    int ko = ks * 128;
    gload16(aS0 + ko, aD0);
    gload16(aS1 + ko, aD1);
    gload16(bS0 + ko, bD0);
    gload16(bS1 + ko, bD1);
    gload16(bS2 + ko, bD2);
    gload16(bS3 + ko, bD3);
    __syncthreads();
    #pragma unroll
    for (int k2 = 0; k2 < 2; ++k2) {
      bf16x8 af[4], bfr[4];
      #pragma unroll
      for (int m = 0; m < 4; ++m) {
        int row = wr*64 + m*16 + lr;
        int bo = (k2*64 + lg*16) ^ ((row & 7) << 4);
        af[m] = *(const bf16x8*)((const char*)As + row*128 + bo);
      }
      #pragma unroll
      for (int n = 0; n < 4; ++n) {
        int row = wc*64 + n*16 + lr;
        int bo = (k2*64 + lg*16) ^ ((row & 7) << 4);
        bfr[n] = *(const bf16x8*)((const char*)Bs + row*128 + bo);
      }
      #pragma unroll
      for (int m = 0; m < 4; ++m)
        #pragma unroll
        for (int n = 0; n < 4; ++n)
          acc[m][n] = __builtin_amdgcn_mfma_f32_16x16x32_bf16(af[m], bfr[n], acc[m][n], 0, 0, 0);
    }
  }

  int rbase = wr*64, cbase = n0 + wc*64;
  const float* b1e = b1 + (size_t)e * ID;
  float b1v[4];
  #pragma unroll
  for (int n = 0; n < 4; ++n) b1v[n] = b1e[cbase + n*16 + lr];
  size_t hrow0 = (size_t)tile * BMF;
  #pragma unroll
  for (int m = 0; m < 4; ++m) {
    #pragma unroll
    for (int j = 0; j < 4; ++j) {
      int row = rbase + m*16 + lg*4 + j;
      float g = gws_s[row];
      u16* hp = hbuf + (hrow0 + row) * ID + cbase + lr;
      #pragma unroll
      for (int n = 0; n < 4; ++n) {
        float v = acc[m][n][j] + b1v[n];
        hp[n*16] = f2bf(gelu_fast(v) * g);
      }
    }
  }
}

// ------- GEMM2: out[tok] += h @ w2 + g*b2   (bf16 MFMA, BN=128, 4 blocks/CU) -------
__global__ __launch_bounds__(512, 2) void moe_gemm2_kernel(
    const u16* __restrict__ hbuf, const u16* __restrict__ w2t,
    const float* __restrict__ b2, const int* __restrict__ offs,
    const int* __restrict__ tilesc, const int* __restrict__ ptok,
    const float* __restrict__ pwv, float* __restrict__ out, int t0)
{
  __shared__ __align__(16) u16 As[BMF*BKF];   // 16 KB
  __shared__ __align__(16) u16 Bs[BN2*BKF];   // 16 KB
  __shared__ int   toks_s[BMF];
  __shared__ float gws_s[BMF];

  int wkid = xcd_swz_2d();
  int tile = wkid % gridDim.x;
  int n0   = (wkid / gridDim.x) * BN2;

  int t = t0 + tile;
  if (t >= tilesc[NE]) return;
  int e = 0;
  #pragma unroll
  for (int k = 1; k < NE; ++k) if (t >= tilesc[k]) e = k;
  int row0 = offs[e] + (t - tilesc[e]) * BMF;
  int nrows = offs[e+1] - row0; if (nrows > BMF) nrows = BMF;
  int tid = threadIdx.x, wid = tid >> 6, lane = tid & 63;

  if (tid < BMF) {
    int tk = -1; float g = 0.f;
    if (tid < nrows) { tk = ptok[row0 + tid]; g = pwv[row0 + tid]; }
    toks_s[tid] = tk; gws_s[tid] = g;
  }
  __syncthreads();

  int ssub = tid >> 3;
  int sbc  = (tid & 7) << 4;
  int swz  = sbc ^ ((ssub & 7) << 4);
  const char* aS0 = (const char*)hbuf + ((size_t)tile*BMF +       ssub) * (ID*2) + swz;
  const char* aS1 = (const char*)hbuf + ((size_t)tile*BMF +  64 + ssub) * (ID*2) + swz;
  const char* bS0 = (const char*)w2t + ((size_t)e*HD + n0 +       ssub) * (ID*2) + swz;
  const char* bS1 = (const char*)w2t + ((size_t)e*HD + n0 +  64 + ssub) * (ID*2) + swz;
  u16* aD0 = As + wid*512;
  u16* aD1 = As + 4096 + wid*512;
  u16* bD0 = Bs + wid*512;
  u16* bD1 = Bs + 4096 + wid*512;

  int wr = wid >> 2, wc = wid & 3;    // 2 x 4 wave grid, 64x32 per wave
  int lr = lane & 15, lg = lane >> 4;

  f32x4 acc[4][2];
  #pragma unroll
  for (int m = 0; m < 4; ++m)
    #pragma unroll
    for (int n = 0; n < 2; ++n) { f32x4 zz = {0.f,0.f,0.f,0.f}; acc[m][n] = zz; }

  for (int ks = 0; ks < ID/BKF; ++ks) {   // 48
    __syncthreads();
    int ko = ks * 128;
    gload16(aS0 + ko, aD0);
    gload16(aS1 + ko, aD1);
    gload16(bS0 + ko, bD0);
    gload16(bS1 + ko, bD1);
    __syncthreads();
    #pragma unroll
    for (int k2 = 0; k2 < 2; ++k2) {
      bf16x8 af[4], bfr[2];
      #pragma unroll
      for (int m = 0; m < 4; ++m) {
        int row = wr*64 + m*16 + lr;
        int bo = (k2*64 + lg*16) ^ ((row & 7) << 4);
        af[m] = *(const bf16x8*)((const char*)As + row*128 + bo);
      }
      #pragma unroll
      for (int n = 0; n < 2; ++n) {
        int row = wc*32 + n*16 + lr;
        int bo = (k2*64 + lg*16) ^ ((row & 7) << 4);
        bfr[n] = *(const bf16x8*)((const char*)Bs + row*128 + bo);
      }
      #pragma unroll
      for (int m = 0; m < 4; ++m)
        #pragma unroll
        for (int n = 0; n < 2; ++n)
          acc[m][n] = __builtin_amdgcn_mfma_f32_16x16x32_bf16(af[m], bfr[n], acc[m][n], 0, 0, 0);
    }
  }

  int rbase = wr*64, cbase = n0 + wc*32;
  const float* b2e = b2 + (size_t)e * HD;
  float b2v[2];
  #pragma unroll
  for (int n = 0; n < 2; ++n) b2v[n] = b2e[cbase + n*16 + lr];
  #pragma unroll
  for (int m = 0; m < 4; ++m) {
    #pragma unroll
    for (int j = 0; j < 4; ++j) {
      int row = rbase + m*16 + lg*4 + j;
      int tk = toks_s[row];
      if (tk < 0) continue;
      float g = gws_s[row];
      float* op = out + (size_t)tk * HD + cbase + lr;
      #pragma unroll
      for (int n = 0; n < 2; ++n)
        atomicAdd(&op[n*16], acc[m][n][j] + g * b2v[n]);
    }
  }
}

// ---------------- fallback fused FFN, f32 VALU ----------------
__global__ __launch_bounds__(512, 4) void ffn_kernel(
    const float* __restrict__ x, const float* __restrict__ w1,
    const float* __restrict__ b1, const float* __restrict__ w2,
    const float* __restrict__ b2, const int* __restrict__ offs,
    const int* __restrict__ tilesc, const int* __restrict__ ptok,
    const float* __restrict__ pwv, float* __restrict__ out)
{
  __shared__ u16 x_t[HD][LDP];
  __shared__ u16 h_t[KCH][LDP];
  __shared__ int   toks[BMS];
  __shared__ float gws[BMS];

  int bid = blockIdx.x;
  if (bid >= tilesc[NE]) return;
  int e = 0;
  #pragma unroll
  for (int k = 1; k < NE; ++k) if (bid >= tilesc[k]) e = k;
  int tile = bid - tilesc[e];
  int row0 = offs[e] + tile * BMS;
  int nrows = offs[e+1] - row0;
  if (nrows > BMS) nrows = BMS;

  int tid = threadIdx.x;
  if (tid < BMS) {
    int tk = -1; float g = 0.f;
    if (tid < nrows) { tk = ptok[row0 + tid]; g = pwv[row0 + tid]; }
    toks[tid] = tk; gws[tid] = g;
  }
  __syncthreads();

  for (int idx = tid; idx < BMS*HD; idx += 512) {
    int m = idx / HD, h = idx - m*HD;
    int tk = toks[m];
    x_t[h][m] = (tk >= 0) ? f2bf(x[(size_t)tk*HD + h]) : (u16)0;
  }

  int w4 = (tid >> 6) << 2;
  int lane = tid & 63;
  const float* w1e = w1 + (size_t)e * HD * ID;
  const float* w2e = w2 + (size_t)e * ID * HD;
  const float* b1e = b1 + (size_t)e * ID;
  const float* b2e = b2 + (size_t)e * HD;

  float acc[4][12];
  #pragma unroll
  for (int jm = 0; jm < 4; ++jm)
    #pragma unroll
    for (int jn = 0; jn < 12; ++jn) acc[jm][jn] = 0.f;

  __syncthreads();
  float gwr[4];
  #pragma unroll
  for (int jm = 0; jm < 4; ++jm) gwr[jm] = gws[w4 + jm];

  for (int c = 0; c < NCHUNK; ++c) {
    int i0 = c * KCH;
    float hb[4][2];
    #pragma unroll
    for (int jm = 0; jm < 4; ++jm) { hb[jm][0] = 0.f; hb[jm][1] = 0.f; }
    const float* p = w1e + i0 + lane;
    #pragma unroll 4
    for (int h = 0; h < HD; ++h) {
      ushort4 xu = *(const ushort4*)&x_t[h][w4];
      float wv0 = p[0];
      float wv1 = p[64];
      p += ID;
      float x0 = bf2f(xu.x), x1 = bf2f(xu.y), x2 = bf2f(xu.z), x3 = bf2f(xu.w);
      hb[0][0] += x0*wv0; hb[1][0] += x1*wv0; hb[2][0] += x2*wv0; hb[3][0] += x3*wv0;
      hb[0][1] += x0*wv1; hb[1][1] += x1*wv1; hb[2][1] += x2*wv1; hb[3][1] += x3*wv1;
    }
    float b1v0 = b1e[i0 + lane];
    float b1v1 = b1e[i0 + 64 + lane];
    __syncthreads();
    #pragma unroll
    for (int q = 0; q < 2; ++q) {
      int il = lane + 64*q;
      float bv = q ? b1v1 : b1v0;
      #pragma unroll
      for (int jm = 0; jm < 4; ++jm) {
        float v = hb[jm][q] + bv;
        v = 0.5f * v * (1.f + erff(v * 0.70710678118654752f));
        h_t[il][w4 + jm] = f2bf(v * gwr[jm]);
      }
    }
    __syncthreads();
    const float* q2 = w2e + (size_t)i0 * HD + lane;
    for (int k = 0; k < KCH; ++k) {
      ushort4 hu = *(const ushort4*)&h_t[k][w4];
      float h0 = bf2f(hu.x), h1 = bf2f(hu.y), h2 = bf2f(hu.z), h3 = bf2f(hu.w);
      #pragma unroll
      for (int jn = 0; jn < 12; ++jn) {
        float wv = q2[64*jn];
        acc[0][jn] += h0*wv; acc[1][jn] += h1*wv;
        acc[2][jn] += h2*wv; acc[3][jn] += h3*wv;
      }
      q2 += HD;
    }
  }

  #pragma unroll
  for (int jm = 0; jm < 4; ++jm) {
    int m = w4 + jm;
    int tk = toks[m];
    if (tk < 0) continue;
    float g = gwr[jm];
    float* orow = out + (size_t)tk * HD;
    #pragma unroll
    for (int jn = 0; jn < 12; ++jn) {
      int n = lane + 64*jn;
      atomicAdd(&orow[n], acc[jm][jn] + g * b2e[n]);
    }
  }
}

extern "C" void kernel_launch(void* const* d_in, const int* in_sizes, int n_in,
                              void* d_out, int out_size, void* d_ws, size_t ws_size,
                              hipStream_t stream)
{
  const float* x  = (const float*)d_in[0];
  const float* rw = (const float*)d_in[1];
  const float* rb = (const float*)d_in[2];
  const float* w1 = (const float*)d_in[3];
  const float* b1 = (const float*)d_in[4];
  const float* w2 = (const float*)d_in[5];
  const float* b2 = (const float*)d_in[6];

  float* out    = (float*)d_out;
  float* aux    = out + (size_t)NTOK * HD;
  float* gating = aux + 1;

  int*   W  = (int*)d_ws;
  float* Wf = (float*)d_ws;
  int*   offs   = W + 16;
  int*   tilesc = W + 32;
  int*   topi   = W + 64;
  float* topw   = Wf + 64 + NPAIR;
  int*   ptok   = W + 64 + 2*NPAIR;
  float* pwv    = Wf + 64 + 3*NPAIR;
  char*  wsB    = (char*)d_ws;
  const size_t OFF_XBF = 262400;
  const size_t OFF_W1T = OFF_XBF + (size_t)NTOK*HD*2;
  const size_t OFF_W2T = OFF_W1T + (size_t)NE*ID*HD*2;
  const size_t OFF_H   = OFF_W2T + (size_t)NE*ID*HD*2;      // 88342784
  const size_t NEED_FULL = OFF_H + (size_t)MAXTF*BMF*ID*2;  // ~195.3 MB

  u16* xbf = (u16*)(wsB + OFF_XBF);
  u16* w1t = (u16*)(wsB + OFF_W1T);
  u16* w2t = (u16*)(wsB + OFF_W2T);
  u16* hb  = (u16*)(wsB + OFF_H);

  hipMemsetAsync(d_out, 0, (size_t)NTOK * HD * sizeof(float), stream);

  router_kernel<<<NTOK/4, 256, 0, stream>>>(x, rw, rb, gating, topi, topw);

  if (ws_size >= NEED_FULL) {
    plan_kernel<<<1, 1024, 0, stream>>>(topi, topw, offs, tilesc, ptok, pwv, BMF, aux);
    cvt_x_kernel<<<(NTOK*HD)/(8*256), 256, 0, stream>>>(x, xbf);
    transpose_bf16_kernel<<<dim3(ID/64, HD/64, NE), 256, 0, stream>>>(w1, w1t, HD, ID);
    transpose_bf16_kernel<<<dim3(HD/64, ID/64, NE), 256, 0, stream>>>(w2, w2t, ID, HD);
    moe_gemm1_kernel<<<dim3(MAXTF, ID/BNF), 512, 0, stream>>>(
        xbf, w1t, b1, offs, tilesc, ptok, pwv, hb, 0);
    moe_gemm2_kernel<<<dim3(MAXTF, HD/BN2), 512, 0, stream>>>(
        hb, w2t, b2, offs, tilesc, ptok, pwv, out, 0);
  } else {
    plan_kernel<<<1, 1024, 0, stream>>>(topi, topw, offs, tilesc, ptok, pwv, BMS, aux);
    ffn_kernel<<<MAXTS, 512, 0, stream>>>(x, w1, b1, w2, b2, offs, tilesc, ptok, pwv, out);
  }
}

// Round 9
// 320.806 us; speedup vs baseline: 1.1628x; 1.1628x over previous
//
#include <hip/hip_runtime.h>
#include <math.h>

#define NB 4
#define NS 2048
#define HD 768
#define ID 3072
#define NE 8
#define NTOK (NB*NS)      // 8192
#define NPAIR (NTOK*2)    // 16384

// ---- fast path tiling ----
#define BMF 128
#define BN1 128            // gemm1 N tile (m103-best 128^2)
#define BNF 256            // gemm2 N tile (round-4 winner)
#define BKF 64
#define MAXTF 136          // max tiles: 128 full + 8 partial

// ---- fallback tiling ----
#define BMS 32
#define KCH 128
#define NCHUNK (ID/KCH)
#define MAXTS (NPAIR/BMS + NE)   // 520
#define LDP 36

typedef unsigned short u16;
typedef __attribute__((ext_vector_type(8))) short bf16x8;
typedef __attribute__((ext_vector_type(4))) float f32x4;

__device__ __forceinline__ float bf2f(u16 u) {
  union { unsigned int i; float f; } v; v.i = ((unsigned int)u) << 16; return v.f;
}
__device__ __forceinline__ u16 f2bf(float f) {
  union { float fl; unsigned int i; } v; v.fl = f;
  unsigned int r = v.i + 0x7fffu + ((v.i >> 16) & 1u);   // RNE
  return (u16)(r >> 16);
}
__device__ __forceinline__ void gload16(const void* g, void* l) {
  __builtin_amdgcn_global_load_lds(
      (const __attribute__((address_space(1))) void*)g,
      (__attribute__((address_space(3))) void*)l, 16, 0, 0);
}
__device__ __forceinline__ float gelu_fast(float x) {
  float u = 0.7978845608028654f * (x + 0.044715f * x * x * x);
  float e = __expf(2.f * u);
  float t = 1.f - 2.f / (e + 1.f);
  return 0.5f * x * (1.f + t);
}
// bijective XCD-chunk swizzle over a 2D grid (m204 variant)
__device__ __forceinline__ int xcd_swz_2d() {
  int nwg  = gridDim.x * gridDim.y;
  int orig = blockIdx.x + blockIdx.y * gridDim.x;
  int q = nwg >> 3, r = nwg & 7;
  int xcd = orig & 7, i = orig >> 3;
  return (xcd < r) ? (xcd * (q + 1) + i) : (r * (q + 1) + (xcd - r) * q + i);
}

// -------- router: 1 wave per token, NO atomics; also emits x as bf16 --------
__global__ __launch_bounds__(256) void router_kernel(
    const float* __restrict__ x, const float* __restrict__ rw,
    const float* __restrict__ rb, float* __restrict__ gating,
    int* __restrict__ topi, float* __restrict__ topw, u16* __restrict__ xb)
{
  int wid = threadIdx.x >> 6, lane = threadIdx.x & 63;
  int tok = blockIdx.x * 4 + wid;
  float acc[NE];
  #pragma unroll
  for (int e = 0; e < NE; ++e) acc[e] = 0.f;
  const float* xr = x + (size_t)tok * HD;
  float4 xq[3];
  #pragma unroll
  for (int r = 0; r < 3; ++r) {
    int h4 = (r*64 + lane) * 4;
    float4 xv = *(const float4*)&xr[h4];
    xq[r] = xv;
    const float4* wr = (const float4*)(rw + (size_t)h4 * NE);
    float4 a0 = wr[0], c0 = wr[1], a1 = wr[2], c1 = wr[3];
    float4 a2 = wr[4], c2 = wr[5], a3 = wr[6], c3 = wr[7];
    acc[0] += xv.x*a0.x + xv.y*a1.x + xv.z*a2.x + xv.w*a3.x;
    acc[1] += xv.x*a0.y + xv.y*a1.y + xv.z*a2.y + xv.w*a3.y;
    acc[2] += xv.x*a0.z + xv.y*a1.z + xv.z*a2.z + xv.w*a3.z;
    acc[3] += xv.x*a0.w + xv.y*a1.w + xv.z*a2.w + xv.w*a3.w;
    acc[4] += xv.x*c0.x + xv.y*c1.x + xv.z*c2.x + xv.w*c3.x;
    acc[5] += xv.x*c0.y + xv.y*c1.y + xv.z*c2.y + xv.w*c3.y;
    acc[6] += xv.x*c0.z + xv.y*c1.z + xv.z*c2.z + xv.w*c3.z;
    acc[7] += xv.x*c0.w + xv.y*c1.w + xv.z*c2.w + xv.w*c3.w;
  }
  if (xb) {
    u16* xo = xb + (size_t)tok * HD;
    #pragma unroll
    for (int r = 0; r < 3; ++r) {
      int h4 = (r*64 + lane) * 4;
      ushort4 o;
      o.x = f2bf(xq[r].x); o.y = f2bf(xq[r].y);
      o.z = f2bf(xq[r].z); o.w = f2bf(xq[r].w);
      *(ushort4*)&xo[h4] = o;
    }
  }
  #pragma unroll
  for (int off = 1; off < 64; off <<= 1) {
    #pragma unroll
    for (int e = 0; e < NE; ++e) acc[e] += __shfl_xor(acc[e], off);
  }
  float lg[NE];
  #pragma unroll
  for (int e = 0; e < NE; ++e) lg[e] = acc[e] + rb[e];
  int i0 = 0;
  #pragma unroll
  for (int e = 1; e < NE; ++e) if (lg[e] > lg[i0]) i0 = e;
  int i1 = (i0 == 0) ? 1 : 0;
  #pragma unroll
  for (int e = 0; e < NE; ++e) if (e != i0 && lg[e] > lg[i1]) i1 = e;
  float ex = expf(lg[i1] - lg[i0]);
  float s = 1.f + ex;
  float w0 = 1.f / s, w1v = ex / s;
  if (lane < NE)
    gating[(size_t)tok*NE + lane] = (lane==i0) ? w0 : (lane==i1 ? w1v : 0.f);
  if (lane == 0) {
    topi[2*tok] = i0; topi[2*tok+1] = i1;
    topw[2*tok] = w0; topw[2*tok+1] = w1v;
  }
}

// ---------- plan: counts + offsets + deterministic scatter + aux loss ----------
__global__ __launch_bounds__(1024) void plan_kernel(
    const int* __restrict__ topi, const float* __restrict__ topw,
    int* __restrict__ offs, int* __restrict__ tilesc,
    int* __restrict__ ptok, float* __restrict__ pwv, int bm,
    float* __restrict__ aux)
{
  __shared__ int   wcnt[16][NE];
  __shared__ int   wbase[16][NE];
  __shared__ float wsum[16][NE];
  int tid = threadIdx.x, w = tid >> 6, lane = tid & 63;
  int base = w * 1024;

  int cnt[NE];
  #pragma unroll
  for (int e = 0; e < NE; ++e) cnt[e] = 0;
  #pragma unroll
  for (int it = 0; it < 16; ++it) {
    int ti = topi[base + it*64 + lane];
    #pragma unroll
    for (int e = 0; e < NE; ++e) {
      unsigned long long m = __ballot(ti == e);
      cnt[e] += __popcll(m);
    }
  }
  if (lane == 0)
    #pragma unroll
    for (int e = 0; e < NE; ++e) wcnt[w][e] = cnt[e];
  __syncthreads();

  if (tid == 0) {
    int o = 0, tt = 0;
    for (int e = 0; e < NE; ++e) {
      offs[e] = o; tilesc[e] = tt;
      int run = o, tot = 0;
      for (int ww = 0; ww < 16; ++ww) { wbase[ww][e] = run; run += wcnt[ww][e]; tot += wcnt[ww][e]; }
      o += tot;
      tt += (tot + bm - 1) / bm;
    }
    offs[NE] = o; tilesc[NE] = tt;
  }
  __syncthreads();

  int run[NE];
  float lsum[NE];
  #pragma unroll
  for (int e = 0; e < NE; ++e) { run[e] = wbase[w][e]; lsum[e] = 0.f; }
  unsigned long long lt = (1ull << lane) - 1ull;
  #pragma unroll
  for (int it = 0; it < 16; ++it) {
    int p = base + it*64 + lane;
    int ti = topi[p];
    float tw = topw[p];
    int idx = 0;
    #pragma unroll
    for (int e = 0; e < NE; ++e) {
      unsigned long long m = __ballot(ti == e);
      int r = run[e] + __popcll(m & lt);
      if (ti == e) idx = r;
      run[e] += __popcll(m);
      lsum[e] += (ti == e) ? tw : 0.f;
    }
    ptok[idx] = p >> 1;
    pwv[idx] = tw;
  }
  #pragma unroll
  for (int off = 1; off < 64; off <<= 1) {
    #pragma unroll
    for (int e = 0; e < NE; ++e) lsum[e] += __shfl_xor(lsum[e], off);
  }
  if (lane == 0)
    #pragma unroll
    for (int e = 0; e < NE; ++e) wsum[w][e] = lsum[e];
  __syncthreads();
  if (tid == 0) {
    float imp[NE];
    for (int e = 0; e < NE; ++e) {
      float s = 0.f;
      for (int ww = 0; ww < 16; ++ww) s += wsum[ww][e];
      imp[e] = s;
    }
    float mean = 0.f;
    for (int e = 0; e < NE; ++e) mean += imp[e];
    mean *= (1.f/NE);
    float var = 0.f;
    for (int e = 0; e < NE; ++e) { float d = imp[e] - mean; var += d*d; }
    var *= (1.f/(NE-1));                       // ddof=1
    aux[0] = 0.01f * var / (mean*mean + 1e-8f);
  }
}

// ---------------- per-expert transpose f32[R][C] -> bf16[C][R] ----------------
__global__ __launch_bounds__(256) void transpose_bf16_kernel(
    const float* __restrict__ src, u16* __restrict__ dst, int R, int C)
{
  __shared__ u16 tile[64][65];
  int e = blockIdx.z;
  const float* s = src + (size_t)e * R * C;
  u16* d = dst + (size_t)e * R * C;
  int c0 = blockIdx.x * 64, r0 = blockIdx.y * 64;
  int t = threadIdx.x;
  int rr = t >> 4, c4 = (t & 15) * 4;
  #pragma unroll
  for (int rep = 0; rep < 4; ++rep) {
    int r = rr + rep * 16;
    float4 v = *(const float4*)&s[(size_t)(r0 + r) * C + c0 + c4];
    tile[r][c4+0] = f2bf(v.x); tile[r][c4+1] = f2bf(v.y);
    tile[r][c4+2] = f2bf(v.z); tile[r][c4+3] = f2bf(v.w);
  }
  __syncthreads();
  #pragma unroll
  for (int rep = 0; rep < 4; ++rep) {
    int w = t + rep * 256;
    int c = w >> 4, rq = (w & 15) * 4;
    ushort4 o;
    o.x = tile[rq+0][c]; o.y = tile[rq+1][c];
    o.z = tile[rq+2][c]; o.w = tile[rq+3][c];
    *(ushort4*)&d[(size_t)(c0 + c) * R + r0 + rq] = o;
  }
}

// ------- GEMM1: h = gelu(X @ w1 + b1) * gate  (bf16 MFMA, 128x128 m97 tile) -------
__global__ __launch_bounds__(256, 3) void moe_gemm1_kernel(
    const u16* __restrict__ xbf, const u16* __restrict__ w1t,
    const float* __restrict__ b1, const int* __restrict__ offs,
    const int* __restrict__ tilesc, const int* __restrict__ ptok,
    const float* __restrict__ pwv, u16* __restrict__ hbuf, int t0)
{
  __shared__ __align__(16) u16 As[BMF*BKF];   // 16 KB, src-swizzled
  __shared__ __align__(16) u16 Bs[BN1*BKF];   // 16 KB, src-swizzled
  __shared__ int   toks_s[BMF];
  __shared__ float gws_s[BMF];

  int wkid = xcd_swz_2d();
  int tile = wkid % gridDim.x;        // tile fastest: same-n0 neighbors on one XCD
  int n0   = (wkid / gridDim.x) * BN1;

  int t = t0 + tile;
  if (t >= tilesc[NE]) return;
  int e = 0;
  #pragma unroll
  for (int k = 1; k < NE; ++k) if (t >= tilesc[k]) e = k;
  int row0 = offs[e] + (t - tilesc[e]) * BMF;
  int nrows = offs[e+1] - row0; if (nrows > BMF) nrows = BMF;
  int tid = threadIdx.x, wid = tid >> 6, lane = tid & 63;

  if (tid < BMF) {
    int tk = -1; float g = 0.f;
    if (tid < nrows) { tk = ptok[row0 + tid]; g = pwv[row0 + tid]; }
    toks_s[tid] = tk; gws_s[tid] = g;
  }
  __syncthreads();

  // staging: 4 gload groups per operand; group g covers rows g*32 + (tid>>3)
  int srow = tid >> 3;                  // 0..31
  int swz  = ((tid & 7) << 4) ^ ((srow & 7) << 4);
  const char* aS[4]; const char* bS[4];
  u16* aD[4]; u16* bD[4];
  #pragma unroll
  for (int g = 0; g < 4; ++g) {
    int tk = toks_s[g*32 + srow]; if (tk < 0) tk = 0;
    aS[g] = (const char*)xbf + (size_t)tk * (HD*2) + swz;
    bS[g] = (const char*)w1t + ((size_t)e*ID + n0 + g*32 + srow) * (HD*2) + swz;
    aD[g] = As + g*2048 + wid*512;      // wave-uniform base; HW adds lane*16B
    bD[g] = Bs + g*2048 + wid*512;
  }

  int wr = wid >> 1, wc = wid & 1;      // 2 x 2 wave grid, 64x64 per wave
  int lr = lane & 15, lg = lane >> 4;

  f32x4 acc[4][4];
  #pragma unroll
  for (int m = 0; m < 4; ++m)
    #pragma unroll
    for (int n = 0; n < 4; ++n) { f32x4 z = {0.f,0.f,0.f,0.f}; acc[m][n] = z; }

  for (int ks = 0; ks < HD/BKF; ++ks) {   // 12
    __syncthreads();
    int ko = ks * 128;
    #pragma unroll
    for (int g = 0; g < 4; ++g) gload16(aS[g] + ko, aD[g]);
    #pragma unroll
    for (int g = 0; g < 4; ++g) gload16(bS[g] + ko, bD[g]);
    __syncthreads();
    #pragma unroll
    for (int k2 = 0; k2 < 2; ++k2) {
      bf16x8 af[4], bfr[4];
      #pragma unroll
      for (int m = 0; m < 4; ++m) {
        int row = wr*64 + m*16 + lr;
        int bo = (k2*64 + lg*16) ^ ((row & 7) << 4);
        af[m] = *(const bf16x8*)((const char*)As + row*128 + bo);
      }
      #pragma unroll
      for (int n = 0; n < 4; ++n) {
        int row = wc*64 + n*16 + lr;
        int bo = (k2*64 + lg*16) ^ ((row & 7) << 4);
        bfr[n] = *(const bf16x8*)((const char*)Bs + row*128 + bo);
      }
      #pragma unroll
      for (int m = 0; m < 4; ++m)
        #pragma unroll
        for (int n = 0; n < 4; ++n)
          acc[m][n] = __builtin_amdgcn_mfma_f32_16x16x32_bf16(af[m], bfr[n], acc[m][n], 0, 0, 0);
    }
  }

  int rbase = wr*64, cbase = n0 + wc*64;
  const float* b1e = b1 + (size_t)e * ID;
  float b1v[4];
  #pragma unroll
  for (int n = 0; n < 4; ++n) b1v[n] = b1e[cbase + n*16 + lr];
  size_t hrow0 = (size_t)tile * BMF;
  #pragma unroll
  for (int m = 0; m < 4; ++m) {
    #pragma unroll
    for (int j = 0; j < 4; ++j) {
      int row = rbase + m*16 + lg*4 + j;
      float g = gws_s[row];
      u16* hp = hbuf + (hrow0 + row) * ID + cbase + lr;
      #pragma unroll
      for (int n = 0; n < 4; ++n) {
        float v = acc[m][n][j] + b1v[n];
        hp[n*16] = f2bf(gelu_fast(v) * g);
      }
    }
  }
}

// ------- GEMM2: out[tok] += h @ w2 + g*b2  (bf16 MFMA, round-4 winner + swizzle) -------
__global__ __launch_bounds__(512, 2) void moe_gemm2_kernel(
    const u16* __restrict__ hbuf, const u16* __restrict__ w2t,
    const float* __restrict__ b2, const int* __restrict__ offs,
    const int* __restrict__ tilesc, const int* __restrict__ ptok,
    const float* __restrict__ pwv, float* __restrict__ out, int t0)
{
  __shared__ __align__(16) u16 As[BMF*BKF];   // 16 KB
  __shared__ __align__(16) u16 Bs[BNF*BKF];   // 32 KB
  __shared__ int   toks_s[BMF];
  __shared__ float gws_s[BMF];

  int wkid = xcd_swz_2d();
  int tile = wkid % gridDim.x;
  int n0   = (wkid / gridDim.x) * BNF;

  int t = t0 + tile;
  if (t >= tilesc[NE]) return;
  int e = 0;
  #pragma unroll
  for (int k = 1; k < NE; ++k) if (t >= tilesc[k]) e = k;
  int row0 = offs[e] + (t - tilesc[e]) * BMF;
  int nrows = offs[e+1] - row0; if (nrows > BMF) nrows = BMF;
  int tid = threadIdx.x, wid = tid >> 6, lane = tid & 63;

  if (tid < BMF) {
    int tk = -1; float g = 0.f;
    if (tid < nrows) { tk = ptok[row0 + tid]; g = pwv[row0 + tid]; }
    toks_s[tid] = tk; gws_s[tid] = g;
  }
  __syncthreads();

  int ssub = tid >> 3;
  int sbc  = (tid & 7) << 4;
  int swz  = sbc ^ ((ssub & 7) << 4);
  const char* aS0 = (const char*)hbuf + ((size_t)tile*BMF +       ssub) * (ID*2) + swz;
  const char* aS1 = (const char*)hbuf + ((size_t)tile*BMF +  64 + ssub) * (ID*2) + swz;
  const char* bS0 = (const char*)w2t + ((size_t)e*HD + n0 +       ssub) * (ID*2) + swz;
  const char* bS1 = (const char*)w2t + ((size_t)e*HD + n0 +  64 + ssub) * (ID*2) + swz;
  const char* bS2 = (const char*)w2t + ((size_t)e*HD + n0 + 128 + ssub) * (ID*2) + swz;
  const char* bS3 = (const char*)w2t + ((size_t)e*HD + n0 + 192 + ssub) * (ID*2) + swz;
  u16* aD0 = As + wid*512;
  u16* aD1 = As + 4096 + wid*512;
  u16* bD0 = Bs + wid*512;
  u16* bD1 = Bs +  4096 + wid*512;
  u16* bD2 = Bs +  8192 + wid*512;
  u16* bD3 = Bs + 12288 + wid*512;

  int wr = wid >> 2, wc = wid & 3;      // 2 x 4 wave grid, 64x64 per wave
  int lr = lane & 15, lg = lane >> 4;

  f32x4 acc[4][4];
  #pragma unroll
  for (int m = 0; m < 4; ++m)
    #pragma unroll
    for (int n = 0; n < 4; ++n) { f32x4 zz = {0.f,0.f,0.f,0.f}; acc[m][n] = zz; }

  for (int ks = 0; ks < ID/BKF; ++ks) {   // 48
    __syncthreads();
    int ko = ks * 128;
    gload16(aS0 + ko, aD0);
    gload16(aS1 + ko, aD1);
    gload16(bS0 + ko, bD0);
    gload16(bS1 + ko, bD1);
    gload16(bS2 + ko, bD2);
    gload16(bS3 + ko, bD3);
    __syncthreads();
    #pragma unroll
    for (int k2 = 0; k2 < 2; ++k2) {
      bf16x8 af[4], bfr[4];
      #pragma unroll
      for (int m = 0; m < 4; ++m) {
        int row = wr*64 + m*16 + lr;
        int bo = (k2*64 + lg*16) ^ ((row & 7) << 4);
        af[m] = *(const bf16x8*)((const char*)As + row*128 + bo);
      }
      #pragma unroll
      for (int n = 0; n < 4; ++n) {
        int row = wc*64 + n*16 + lr;
        int bo = (k2*64 + lg*16) ^ ((row & 7) << 4);
        bfr[n] = *(const bf16x8*)((const char*)Bs + row*128 + bo);
      }
      #pragma unroll
      for (int m = 0; m < 4; ++m)
        #pragma unroll
        for (int n = 0; n < 4; ++n)
          acc[m][n] = __builtin_amdgcn_mfma_f32_16x16x32_bf16(af[m], bfr[n], acc[m][n], 0, 0, 0);
    }
  }

  int rbase = wr*64, cbase = n0 + wc*64;
  const float* b2e = b2 + (size_t)e * HD;
  float b2v[4];
  #pragma unroll
  for (int n = 0; n < 4; ++n) b2v[n] = b2e[cbase + n*16 + lr];
  #pragma unroll
  for (int m = 0; m < 4; ++m) {
    #pragma unroll
    for (int j = 0; j < 4; ++j) {
      int row = rbase + m*16 + lg*4 + j;
      int tk = toks_s[row];
      if (tk < 0) continue;
      float g = gws_s[row];
      float* op = out + (size_t)tk * HD + cbase + lr;
      #pragma unroll
      for (int n = 0; n < 4; ++n)
        atomicAdd(&op[n*16], acc[m][n][j] + g * b2v[n]);
    }
  }
}

// ---------------- fallback fused FFN, f32 VALU ----------------
__global__ __launch_bounds__(512, 4) void ffn_kernel(
    const float* __restrict__ x, const float* __restrict__ w1,
    const float* __restrict__ b1, const float* __restrict__ w2,
    const float* __restrict__ b2, const int* __restrict__ offs,
    const int* __restrict__ tilesc, const int* __restrict__ ptok,
    const float* __restrict__ pwv, float* __restrict__ out)
{
  __shared__ u16 x_t[HD][LDP];
  __shared__ u16 h_t[KCH][LDP];
  __shared__ int   toks[BMS];
  __shared__ float gws[BMS];

  int bid = blockIdx.x;
  if (bid >= tilesc[NE]) return;
  int e = 0;
  #pragma unroll
  for (int k = 1; k < NE; ++k) if (bid >= tilesc[k]) e = k;
  int tile = bid - tilesc[e];
  int row0 = offs[e] + tile * BMS;
  int nrows = offs[e+1] - row0;
  if (nrows > BMS) nrows = BMS;

  int tid = threadIdx.x;
  if (tid < BMS) {
    int tk = -1; float g = 0.f;
    if (tid < nrows) { tk = ptok[row0 + tid]; g = pwv[row0 + tid]; }
    toks[tid] = tk; gws[tid] = g;
  }
  __syncthreads();

  for (int idx = tid; idx < BMS*HD; idx += 512) {
    int m = idx / HD, h = idx - m*HD;
    int tk = toks[m];
    x_t[h][m] = (tk >= 0) ? f2bf(x[(size_t)tk*HD + h]) : (u16)0;
  }

  int w4 = (tid >> 6) << 2;
  int lane = tid & 63;
  const float* w1e = w1 + (size_t)e * HD * ID;
  const float* w2e = w2 + (size_t)e * ID * HD;
  const float* b1e = b1 + (size_t)e * ID;
  const float* b2e = b2 + (size_t)e * HD;

  float acc[4][12];
  #pragma unroll
  for (int jm = 0; jm < 4; ++jm)
    #pragma unroll
    for (int jn = 0; jn < 12; ++jn) acc[jm][jn] = 0.f;

  __syncthreads();
  float gwr[4];
  #pragma unroll
  for (int jm = 0; jm < 4; ++jm) gwr[jm] = gws[w4 + jm];

  for (int c = 0; c < NCHUNK; ++c) {
    int i0 = c * KCH;
    float hb[4][2];
    #pragma unroll
    for (int jm = 0; jm < 4; ++jm) { hb[jm][0] = 0.f; hb[jm][1] = 0.f; }
    const float* p = w1e + i0 + lane;
    #pragma unroll 4
    for (int h = 0; h < HD; ++h) {
      ushort4 xu = *(const ushort4*)&x_t[h][w4];
      float wv0 = p[0];
      float wv1 = p[64];
      p += ID;
      float x0 = bf2f(xu.x), x1 = bf2f(xu.y), x2 = bf2f(xu.z), x3 = bf2f(xu.w);
      hb[0][0] += x0*wv0; hb[1][0] += x1*wv0; hb[2][0] += x2*wv0; hb[3][0] += x3*wv0;
      hb[0][1] += x0*wv1; hb[1][1] += x1*wv1; hb[2][1] += x2*wv1; hb[3][1] += x3*wv1;
    }
    float b1v0 = b1e[i0 + lane];
    float b1v1 = b1e[i0 + 64 + lane];
    __syncthreads();
    #pragma unroll
    for (int q = 0; q < 2; ++q) {
      int il = lane + 64*q;
      float bv = q ? b1v1 : b1v0;
      #pragma unroll
      for (int jm = 0; jm < 4; ++jm) {
        float v = hb[jm][q] + bv;
        v = 0.5f * v * (1.f + erff(v * 0.70710678118654752f));
        h_t[il][w4 + jm] = f2bf(v * gwr[jm]);
      }
    }
    __syncthreads();
    const float* q2 = w2e + (size_t)i0 * HD + lane;
    for (int k = 0; k < KCH; ++k) {
      ushort4 hu = *(const ushort4*)&h_t[k][w4];
      float h0 = bf2f(hu.x), h1 = bf2f(hu.y), h2 = bf2f(hu.z), h3 = bf2f(hu.w);
      #pragma unroll
      for (int jn = 0; jn < 12; ++jn) {
        float wv = q2[64*jn];
        acc[0][jn] += h0*wv; acc[1][jn] += h1*wv;
        acc[2][jn] += h2*wv; acc[3][jn] += h3*wv;
      }
      q2 += HD;
    }
  }

  #pragma unroll
  for (int jm = 0; jm < 4; ++jm) {
    int m = w4 + jm;
    int tk = toks[m];
    if (tk < 0) continue;
    float g = gwr[jm];
    float* orow = out + (size_t)tk * HD;
    #pragma unroll
    for (int jn = 0; jn < 12; ++jn) {
      int n = lane + 64*jn;
      atomicAdd(&orow[n], acc[jm][jn] + g * b2e[n]);
    }
  }
}

extern "C" void kernel_launch(void* const* d_in, const int* in_sizes, int n_in,
                              void* d_out, int out_size, void* d_ws, size_t ws_size,
                              hipStream_t stream)
{
  const float* x  = (const float*)d_in[0];
  const float* rw = (const float*)d_in[1];
  const float* rb = (const float*)d_in[2];
  const float* w1 = (const float*)d_in[3];
  const float* b1 = (const float*)d_in[4];
  const float* w2 = (const float*)d_in[5];
  const float* b2 = (const float*)d_in[6];

  float* out    = (float*)d_out;
  float* aux    = out + (size_t)NTOK * HD;
  float* gating = aux + 1;

  int*   W  = (int*)d_ws;
  float* Wf = (float*)d_ws;
  int*   offs   = W + 16;
  int*   tilesc = W + 32;
  int*   topi   = W + 64;
  float* topw   = Wf + 64 + NPAIR;
  int*   ptok   = W + 64 + 2*NPAIR;
  float* pwv    = Wf + 64 + 3*NPAIR;
  char*  wsB    = (char*)d_ws;
  const size_t OFF_XBF = 262400;
  const size_t OFF_W1T = OFF_XBF + (size_t)NTOK*HD*2;
  const size_t OFF_W2T = OFF_W1T + (size_t)NE*ID*HD*2;
  const size_t OFF_H   = OFF_W2T + (size_t)NE*ID*HD*2;      // 88342784
  const size_t NEED_FULL = OFF_H + (size_t)MAXTF*BMF*ID*2;  // ~195.3 MB

  u16* xbf = (u16*)(wsB + OFF_XBF);
  u16* w1t = (u16*)(wsB + OFF_W1T);
  u16* w2t = (u16*)(wsB + OFF_W2T);
  u16* hb  = (u16*)(wsB + OFF_H);

  bool fast = (ws_size >= NEED_FULL);

  hipMemsetAsync(d_out, 0, (size_t)NTOK * HD * sizeof(float), stream);

  router_kernel<<<NTOK/4, 256, 0, stream>>>(x, rw, rb, gating, topi, topw,
                                            fast ? xbf : (u16*)nullptr);

  if (fast) {
    plan_kernel<<<1, 1024, 0, stream>>>(topi, topw, offs, tilesc, ptok, pwv, BMF, aux);
    transpose_bf16_kernel<<<dim3(ID/64, HD/64, NE), 256, 0, stream>>>(w1, w1t, HD, ID);
    transpose_bf16_kernel<<<dim3(HD/64, ID/64, NE), 256, 0, stream>>>(w2, w2t, ID, HD);
    moe_gemm1_kernel<<<dim3(MAXTF, ID/BN1), 256, 0, stream>>>(
        xbf, w1t, b1, offs, tilesc, ptok, pwv, hb, 0);
    moe_gemm2_kernel<<<dim3(MAXTF, HD/BNF), 512, 0, stream>>>(
        hb, w2t, b2, offs, tilesc, ptok, pwv, out, 0);
  } else {
    plan_kernel<<<1, 1024, 0, stream>>>(topi, topw, offs, tilesc, ptok, pwv, BMS, aux);
    ffn_kernel<<<MAXTS, 512, 0, stream>>>(x, w1, b1, w2, b2, offs, tilesc, ptok, pwv, out);
  }
}

// Round 10
// 302.661 us; speedup vs baseline: 1.2325x; 1.0600x over previous
//
#include <hip/hip_runtime.h>
#include <math.h>

#define NB 4
#define NS 2048
#define HD 768
#define ID 3072
#define NE 8
#define NTOK (NB*NS)      // 8192
#define NPAIR (NTOK*2)    // 16384

// ---- fast path tiling ----
#define BMF 128
#define BN1 128            // gemm1 N tile (m103-best 128^2)
#define BN2 128            // gemm2 N tile (128^2, 256 thr)
#define BKF 64
#define MAXTF 136          // max tiles: 128 full + 8 partial
#define NY1 (ID/BN1)       // 24
#define NY2 (HD/BN2)       // 6

// ---- fallback tiling ----
#define BMS 32
#define KCH 128
#define NCHUNK (ID/KCH)
#define MAXTS (NPAIR/BMS + NE)   // 520
#define LDP 36

typedef unsigned short u16;
typedef __attribute__((ext_vector_type(8))) short bf16x8;
typedef __attribute__((ext_vector_type(4))) float f32x4;

__device__ __forceinline__ float bf2f(u16 u) {
  union { unsigned int i; float f; } v; v.i = ((unsigned int)u) << 16; return v.f;
}
__device__ __forceinline__ u16 f2bf(float f) {
  union { float fl; unsigned int i; } v; v.fl = f;
  unsigned int r = v.i + 0x7fffu + ((v.i >> 16) & 1u);   // RNE
  return (u16)(r >> 16);
}
__device__ __forceinline__ void gload16(const void* g, void* l) {
  __builtin_amdgcn_global_load_lds(
      (const __attribute__((address_space(1))) void*)g,
      (__attribute__((address_space(3))) void*)l, 16, 0, 0);
}
__device__ __forceinline__ float gelu_fast(float x) {
  float u = 0.7978845608028654f * (x + 0.044715f * x * x * x);
  float e = __expf(2.f * u);
  float t = 1.f - 2.f / (e + 1.f);
  return 0.5f * x * (1.f + t);
}
// bijective XCD-chunk swizzle (m204 variant), 1-D grid
__device__ __forceinline__ int xcd_swz_1d() {
  int nwg  = gridDim.x;
  int orig = blockIdx.x;
  int q = nwg >> 3, r = nwg & 7;
  int xcd = orig & 7, i = orig >> 3;
  return (xcd < r) ? (xcd * (q + 1) + i) : (r * (q + 1) + (xcd - r) * q + i);
}

// -------- router body: 1 wave per token, NO atomics; also emits x as bf16 --------
__device__ __forceinline__ void router_body(
    int bid, const float* __restrict__ x, const float* __restrict__ rw,
    const float* __restrict__ rb, float* __restrict__ gating,
    int* __restrict__ topi, float* __restrict__ topw, u16* __restrict__ xb)
{
  int wid = threadIdx.x >> 6, lane = threadIdx.x & 63;
  int tok = bid * 4 + wid;
  float acc[NE];
  #pragma unroll
  for (int e = 0; e < NE; ++e) acc[e] = 0.f;
  const float* xr = x + (size_t)tok * HD;
  float4 xq[3];
  #pragma unroll
  for (int r = 0; r < 3; ++r) {
    int h4 = (r*64 + lane) * 4;
    float4 xv = *(const float4*)&xr[h4];
    xq[r] = xv;
    const float4* wr = (const float4*)(rw + (size_t)h4 * NE);
    float4 a0 = wr[0], c0 = wr[1], a1 = wr[2], c1 = wr[3];
    float4 a2 = wr[4], c2 = wr[5], a3 = wr[6], c3 = wr[7];
    acc[0] += xv.x*a0.x + xv.y*a1.x + xv.z*a2.x + xv.w*a3.x;
    acc[1] += xv.x*a0.y + xv.y*a1.y + xv.z*a2.y + xv.w*a3.y;
    acc[2] += xv.x*a0.z + xv.y*a1.z + xv.z*a2.z + xv.w*a3.z;
    acc[3] += xv.x*a0.w + xv.y*a1.w + xv.z*a2.w + xv.w*a3.w;
    acc[4] += xv.x*c0.x + xv.y*c1.x + xv.z*c2.x + xv.w*c3.x;
    acc[5] += xv.x*c0.y + xv.y*c1.y + xv.z*c2.y + xv.w*c3.y;
    acc[6] += xv.x*c0.z + xv.y*c1.z + xv.z*c2.z + xv.w*c3.z;
    acc[7] += xv.x*c0.w + xv.y*c1.w + xv.z*c2.w + xv.w*c3.w;
  }
  if (xb) {
    u16* xo = xb + (size_t)tok * HD;
    #pragma unroll
    for (int r = 0; r < 3; ++r) {
      int h4 = (r*64 + lane) * 4;
      ushort4 o;
      o.x = f2bf(xq[r].x); o.y = f2bf(xq[r].y);
      o.z = f2bf(xq[r].z); o.w = f2bf(xq[r].w);
      *(ushort4*)&xo[h4] = o;
    }
  }
  #pragma unroll
  for (int off = 1; off < 64; off <<= 1) {
    #pragma unroll
    for (int e = 0; e < NE; ++e) acc[e] += __shfl_xor(acc[e], off);
  }
  float lg[NE];
  #pragma unroll
  for (int e = 0; e < NE; ++e) lg[e] = acc[e] + rb[e];
  int i0 = 0;
  #pragma unroll
  for (int e = 1; e < NE; ++e) if (lg[e] > lg[i0]) i0 = e;
  int i1 = (i0 == 0) ? 1 : 0;
  #pragma unroll
  for (int e = 0; e < NE; ++e) if (e != i0 && lg[e] > lg[i1]) i1 = e;
  float ex = expf(lg[i1] - lg[i0]);
  float s = 1.f + ex;
  float w0 = 1.f / s, w1v = ex / s;
  if (lane < NE)
    gating[(size_t)tok*NE + lane] = (lane==i0) ? w0 : (lane==i1 ? w1v : 0.f);
  if (lane == 0) {
    topi[2*tok] = i0; topi[2*tok+1] = i1;
    topw[2*tok] = w0; topw[2*tok+1] = w1v;
  }
}

// -------- transpose body: f32[R][C] tile (r0,c0) -> bf16[C][R] --------
__device__ __forceinline__ void transpose_body(
    int bx, int by, int e, const float* __restrict__ src, u16* __restrict__ dst,
    int R, int C)
{
  __shared__ u16 tile[64][65];
  const float* s = src + (size_t)e * R * C;
  u16* d = dst + (size_t)e * R * C;
  int c0 = bx * 64, r0 = by * 64;
  int t = threadIdx.x;
  int rr = t >> 4, c4 = (t & 15) * 4;
  #pragma unroll
  for (int rep = 0; rep < 4; ++rep) {
    int r = rr + rep * 16;
    float4 v = *(const float4*)&s[(size_t)(r0 + r) * C + c0 + c4];
    tile[r][c4+0] = f2bf(v.x); tile[r][c4+1] = f2bf(v.y);
    tile[r][c4+2] = f2bf(v.z); tile[r][c4+3] = f2bf(v.w);
  }
  __syncthreads();
  #pragma unroll
  for (int rep = 0; rep < 4; ++rep) {
    int w = t + rep * 256;
    int c = w >> 4, rq = (w & 15) * 4;
    ushort4 o;
    o.x = tile[rq+0][c]; o.y = tile[rq+1][c];
    o.z = tile[rq+2][c]; o.w = tile[rq+3][c];
    *(ushort4*)&d[(size_t)(c0 + c) * R + r0 + rq] = o;
  }
}

// -------- prep: router + both weight transposes in one launch --------
#define NW1T ((ID/64)*(HD/64)*NE)   // 4608
#define NW2T ((HD/64)*(ID/64)*NE)   // 4608
__global__ __launch_bounds__(256) void prep_kernel(
    const float* __restrict__ x, const float* __restrict__ rw,
    const float* __restrict__ rb, float* __restrict__ gating,
    int* __restrict__ topi, float* __restrict__ topw, u16* __restrict__ xb,
    const float* __restrict__ w1, u16* __restrict__ w1t,
    const float* __restrict__ w2, u16* __restrict__ w2t)
{
  int bid = blockIdx.x;
  if (bid < NTOK/4) { router_body(bid, x, rw, rb, gating, topi, topw, xb); return; }
  bid -= NTOK/4;
  if (bid < NW1T) {
    int bx = bid % (ID/64); int rest = bid / (ID/64);
    int by = rest % (HD/64); int e = rest / (HD/64);
    transpose_body(bx, by, e, w1, w1t, HD, ID);
    return;
  }
  bid -= NW1T;
  {
    int bx = bid % (HD/64); int rest = bid / (HD/64);
    int by = rest % (ID/64); int e = rest / (ID/64);
    transpose_body(bx, by, e, w2, w2t, ID, HD);
  }
}

// -------- fallback router (no transposes, no xb) --------
__global__ __launch_bounds__(256) void router_kernel(
    const float* __restrict__ x, const float* __restrict__ rw,
    const float* __restrict__ rb, float* __restrict__ gating,
    int* __restrict__ topi, float* __restrict__ topw)
{
  router_body(blockIdx.x, x, rw, rb, gating, topi, topw, (u16*)nullptr);
}

// ---------- plan: counts + offsets + deterministic scatter + aux loss ----------
__global__ __launch_bounds__(1024) void plan_kernel(
    const int* __restrict__ topi, const float* __restrict__ topw,
    int* __restrict__ offs, int* __restrict__ tilesc,
    int* __restrict__ ptok, float* __restrict__ pwv, int bm,
    float* __restrict__ aux)
{
  __shared__ int   wcnt[16][NE];
  __shared__ int   wbase[16][NE];
  __shared__ float wsum[16][NE];
  int tid = threadIdx.x, w = tid >> 6, lane = tid & 63;
  int base = w * 1024;

  int cnt[NE];
  #pragma unroll
  for (int e = 0; e < NE; ++e) cnt[e] = 0;
  #pragma unroll
  for (int it = 0; it < 16; ++it) {
    int ti = topi[base + it*64 + lane];
    #pragma unroll
    for (int e = 0; e < NE; ++e) {
      unsigned long long m = __ballot(ti == e);
      cnt[e] += __popcll(m);
    }
  }
  if (lane == 0)
    #pragma unroll
    for (int e = 0; e < NE; ++e) wcnt[w][e] = cnt[e];
  __syncthreads();

  if (tid == 0) {
    int o = 0, tt = 0;
    for (int e = 0; e < NE; ++e) {
      offs[e] = o; tilesc[e] = tt;
      int run = o, tot = 0;
      for (int ww = 0; ww < 16; ++ww) { wbase[ww][e] = run; run += wcnt[ww][e]; tot += wcnt[ww][e]; }
      o += tot;
      tt += (tot + bm - 1) / bm;
    }
    offs[NE] = o; tilesc[NE] = tt;
  }
  __syncthreads();

  int run[NE];
  float lsum[NE];
  #pragma unroll
  for (int e = 0; e < NE; ++e) { run[e] = wbase[w][e]; lsum[e] = 0.f; }
  unsigned long long lt = (1ull << lane) - 1ull;
  #pragma unroll
  for (int it = 0; it < 16; ++it) {
    int p = base + it*64 + lane;
    int ti = topi[p];
    float tw = topw[p];
    int idx = 0;
    #pragma unroll
    for (int e = 0; e < NE; ++e) {
      unsigned long long m = __ballot(ti == e);
      int r = run[e] + __popcll(m & lt);
      if (ti == e) idx = r;
      run[e] += __popcll(m);
      lsum[e] += (ti == e) ? tw : 0.f;
    }
    ptok[idx] = p >> 1;
    pwv[idx] = tw;
  }
  #pragma unroll
  for (int off = 1; off < 64; off <<= 1) {
    #pragma unroll
    for (int e = 0; e < NE; ++e) lsum[e] += __shfl_xor(lsum[e], off);
  }
  if (lane == 0)
    #pragma unroll
    for (int e = 0; e < NE; ++e) wsum[w][e] = lsum[e];
  __syncthreads();
  if (tid == 0) {
    float imp[NE];
    for (int e = 0; e < NE; ++e) {
      float s = 0.f;
      for (int ww = 0; ww < 16; ++ww) s += wsum[ww][e];
      imp[e] = s;
    }
    float mean = 0.f;
    for (int e = 0; e < NE; ++e) mean += imp[e];
    mean *= (1.f/NE);
    float var = 0.f;
    for (int e = 0; e < NE; ++e) { float d = imp[e] - mean; var += d*d; }
    var *= (1.f/(NE-1));                       // ddof=1
    aux[0] = 0.01f * var / (mean*mean + 1e-8f);
  }
}

// ------- GEMM1: h = gelu(X @ w1 + b1) * gate  (bf16 MFMA, 128x128, n-fastest) -------
__global__ __launch_bounds__(256, 3) void moe_gemm1_kernel(
    const u16* __restrict__ xbf, const u16* __restrict__ w1t,
    const float* __restrict__ b1, const int* __restrict__ offs,
    const int* __restrict__ tilesc, const int* __restrict__ ptok,
    const float* __restrict__ pwv, u16* __restrict__ hbuf)
{
  __shared__ __align__(16) u16 As[BMF*BKF];   // 16 KB, src-swizzled
  __shared__ __align__(16) u16 Bs[BN1*BKF];   // 16 KB, src-swizzled
  __shared__ int   toks_s[BMF];
  __shared__ float gws_s[BMF];

  int wkid = xcd_swz_1d();
  int tile = wkid / NY1;              // n fastest: all 24 n-blocks of a tile adjacent
  int n0   = (wkid % NY1) * BN1;

  int t = tile;
  if (t >= tilesc[NE]) return;
  int e = 0;
  #pragma unroll
  for (int k = 1; k < NE; ++k) if (t >= tilesc[k]) e = k;
  int row0 = offs[e] + (t - tilesc[e]) * BMF;
  int nrows = offs[e+1] - row0; if (nrows > BMF) nrows = BMF;
  int tid = threadIdx.x, wid = tid >> 6, lane = tid & 63;

  if (tid < BMF) {
    int tk = -1; float g = 0.f;
    if (tid < nrows) { tk = ptok[row0 + tid]; g = pwv[row0 + tid]; }
    toks_s[tid] = tk; gws_s[tid] = g;
  }
  __syncthreads();

  // staging: 4 gload groups per operand; group g covers rows g*32 + (tid>>3)
  int srow = tid >> 3;                  // 0..31
  int swz  = ((tid & 7) << 4) ^ ((srow & 7) << 4);
  const char* aS[4]; const char* bS[4];
  u16* aD[4]; u16* bD[4];
  #pragma unroll
  for (int g = 0; g < 4; ++g) {
    int tk = toks_s[g*32 + srow]; if (tk < 0) tk = 0;
    aS[g] = (const char*)xbf + (size_t)tk * (HD*2) + swz;
    bS[g] = (const char*)w1t + ((size_t)e*ID + n0 + g*32 + srow) * (HD*2) + swz;
    aD[g] = As + g*2048 + wid*512;      // wave-uniform base; HW adds lane*16B
    bD[g] = Bs + g*2048 + wid*512;
  }

  int wr = wid >> 1, wc = wid & 1;      // 2 x 2 wave grid, 64x64 per wave
  int lr = lane & 15, lg = lane >> 4;

  f32x4 acc[4][4];
  #pragma unroll
  for (int m = 0; m < 4; ++m)
    #pragma unroll
    for (int n = 0; n < 4; ++n) { f32x4 z = {0.f,0.f,0.f,0.f}; acc[m][n] = z; }

  for (int ks = 0; ks < HD/BKF; ++ks) {   // 12
    __syncthreads();
    int ko = ks * 128;
    #pragma unroll
    for (int g = 0; g < 4; ++g) gload16(aS[g] + ko, aD[g]);
    #pragma unroll
    for (int g = 0; g < 4; ++g) gload16(bS[g] + ko, bD[g]);
    __syncthreads();
    #pragma unroll
    for (int k2 = 0; k2 < 2; ++k2) {
      bf16x8 af[4], bfr[4];
      #pragma unroll
      for (int m = 0; m < 4; ++m) {
        int row = wr*64 + m*16 + lr;
        int bo = (k2*64 + lg*16) ^ ((row & 7) << 4);
        af[m] = *(const bf16x8*)((const char*)As + row*128 + bo);
      }
      #pragma unroll
      for (int n = 0; n < 4; ++n) {
        int row = wc*64 + n*16 + lr;
        int bo = (k2*64 + lg*16) ^ ((row & 7) << 4);
        bfr[n] = *(const bf16x8*)((const char*)Bs + row*128 + bo);
      }
      #pragma unroll
      for (int m = 0; m < 4; ++m)
        #pragma unroll
        for (int n = 0; n < 4; ++n)
          acc[m][n] = __builtin_amdgcn_mfma_f32_16x16x32_bf16(af[m], bfr[n], acc[m][n], 0, 0, 0);
    }
  }

  int rbase = wr*64, cbase = n0 + wc*64;
  const float* b1e = b1 + (size_t)e * ID;
  float b1v[4];
  #pragma unroll
  for (int n = 0; n < 4; ++n) b1v[n] = b1e[cbase + n*16 + lr];
  size_t hrow0 = (size_t)tile * BMF;
  #pragma unroll
  for (int m = 0; m < 4; ++m) {
    #pragma unroll
    for (int j = 0; j < 4; ++j) {
      int row = rbase + m*16 + lg*4 + j;
      float g = gws_s[row];
      u16* hp = hbuf + (hrow0 + row) * ID + cbase + lr;
      #pragma unroll
      for (int n = 0; n < 4; ++n) {
        float v = acc[m][n][j] + b1v[n];
        hp[n*16] = f2bf(gelu_fast(v) * g);
      }
    }
  }
}

// ------- GEMM2: out[tok] += h @ w2 + g*b2  (bf16 MFMA, 128x128, n-fastest) -------
__global__ __launch_bounds__(256, 4) void moe_gemm2_kernel(
    const u16* __restrict__ hbuf, const u16* __restrict__ w2t,
    const float* __restrict__ b2, const int* __restrict__ offs,
    const int* __restrict__ tilesc, const int* __restrict__ ptok,
    const float* __restrict__ pwv, float* __restrict__ out)
{
  __shared__ __align__(16) u16 As[BMF*BKF];   // 16 KB
  __shared__ __align__(16) u16 Bs[BN2*BKF];   // 16 KB
  __shared__ int   toks_s[BMF];
  __shared__ float gws_s[BMF];

  int wkid = xcd_swz_1d();
  int tile = wkid / NY2;              // n fastest: all 6 n-blocks of a tile adjacent
  int n0   = (wkid % NY2) * BN2;

  int t = tile;
  if (t >= tilesc[NE]) return;
  int e = 0;
  #pragma unroll
  for (int k = 1; k < NE; ++k) if (t >= tilesc[k]) e = k;
  int row0 = offs[e] + (t - tilesc[e]) * BMF;
  int nrows = offs[e+1] - row0; if (nrows > BMF) nrows = BMF;
  int tid = threadIdx.x, wid = tid >> 6, lane = tid & 63;

  if (tid < BMF) {
    int tk = -1; float g = 0.f;
    if (tid < nrows) { tk = ptok[row0 + tid]; g = pwv[row0 + tid]; }
    toks_s[tid] = tk; gws_s[tid] = g;
  }
  __syncthreads();

  int srow = tid >> 3;
  int swz  = ((tid & 7) << 4) ^ ((srow & 7) << 4);
  const char* aS[4]; const char* bS[4];
  u16* aD[4]; u16* bD[4];
  #pragma unroll
  for (int g = 0; g < 4; ++g) {
    aS[g] = (const char*)hbuf + ((size_t)tile*BMF + g*32 + srow) * (ID*2) + swz;
    bS[g] = (const char*)w2t + ((size_t)e*HD + n0 + g*32 + srow) * (ID*2) + swz;
    aD[g] = As + g*2048 + wid*512;
    bD[g] = Bs + g*2048 + wid*512;
  }

  int wr = wid >> 1, wc = wid & 1;      // 2 x 2 wave grid, 64x64 per wave
  int lr = lane & 15, lg = lane >> 4;

  f32x4 acc[4][4];
  #pragma unroll
  for (int m = 0; m < 4; ++m)
    #pragma unroll
    for (int n = 0; n < 4; ++n) { f32x4 z = {0.f,0.f,0.f,0.f}; acc[m][n] = z; }

  for (int ks = 0; ks < ID/BKF; ++ks) {   // 48
    __syncthreads();
    int ko = ks * 128;
    #pragma unroll
    for (int g = 0; g < 4; ++g) gload16(aS[g] + ko, aD[g]);
    #pragma unroll
    for (int g = 0; g < 4; ++g) gload16(bS[g] + ko, bD[g]);
    __syncthreads();
    #pragma unroll
    for (int k2 = 0; k2 < 2; ++k2) {
      bf16x8 af[4], bfr[4];
      #pragma unroll
      for (int m = 0; m < 4; ++m) {
        int row = wr*64 + m*16 + lr;
        int bo = (k2*64 + lg*16) ^ ((row & 7) << 4);
        af[m] = *(const bf16x8*)((const char*)As + row*128 + bo);
      }
      #pragma unroll
      for (int n = 0; n < 4; ++n) {
        int row = wc*64 + n*16 + lr;
        int bo = (k2*64 + lg*16) ^ ((row & 7) << 4);
        bfr[n] = *(const bf16x8*)((const char*)Bs + row*128 + bo);
      }
      #pragma unroll
      for (int m = 0; m < 4; ++m)
        #pragma unroll
        for (int n = 0; n < 4; ++n)
          acc[m][n] = __builtin_amdgcn_mfma_f32_16x16x32_bf16(af[m], bfr[n], acc[m][n], 0, 0, 0);
    }
  }

  int rbase = wr*64, cbase = n0 + wc*64;
  const float* b2e = b2 + (size_t)e * HD;
  float b2v[4];
  #pragma unroll
  for (int n = 0; n < 4; ++n) b2v[n] = b2e[cbase + n*16 + lr];
  #pragma unroll
  for (int m = 0; m < 4; ++m) {
    #pragma unroll
    for (int j = 0; j < 4; ++j) {
      int row = rbase + m*16 + lg*4 + j;
      int tk = toks_s[row];
      if (tk < 0) continue;
      float g = gws_s[row];
      float* op = out + (size_t)tk * HD + cbase + lr;
      #pragma unroll
      for (int n = 0; n < 4; ++n)
        atomicAdd(&op[n*16], acc[m][n][j] + g * b2v[n]);
    }
  }
}

// ---------------- fallback fused FFN, f32 VALU ----------------
__global__ __launch_bounds__(512, 4) void ffn_kernel(
    const float* __restrict__ x, const float* __restrict__ w1,
    const float* __restrict__ b1, const float* __restrict__ w2,
    const float* __restrict__ b2, const int* __restrict__ offs,
    const int* __restrict__ tilesc, const int* __restrict__ ptok,
    const float* __restrict__ pwv, float* __restrict__ out)
{
  __shared__ u16 x_t[HD][LDP];
  __shared__ u16 h_t[KCH][LDP];
  __shared__ int   toks[BMS];
  __shared__ float gws[BMS];

  int bid = blockIdx.x;
  if (bid >= tilesc[NE]) return;
  int e = 0;
  #pragma unroll
  for (int k = 1; k < NE; ++k) if (bid >= tilesc[k]) e = k;
  int tile = bid - tilesc[e];
  int row0 = offs[e] + tile * BMS;
  int nrows = offs[e+1] - row0;
  if (nrows > BMS) nrows = BMS;

  int tid = threadIdx.x;
  if (tid < BMS) {
    int tk = -1; float g = 0.f;
    if (tid < nrows) { tk = ptok[row0 + tid]; g = pwv[row0 + tid]; }
    toks[tid] = tk; gws[tid] = g;
  }
  __syncthreads();

  for (int idx = tid; idx < BMS*HD; idx += 512) {
    int m = idx / HD, h = idx - m*HD;
    int tk = toks[m];
    x_t[h][m] = (tk >= 0) ? f2bf(x[(size_t)tk*HD + h]) : (u16)0;
  }

  int w4 = (tid >> 6) << 2;
  int lane = tid & 63;
  const float* w1e = w1 + (size_t)e * HD * ID;
  const float* w2e = w2 + (size_t)e * ID * HD;
  const float* b1e = b1 + (size_t)e * ID;
  const float* b2e = b2 + (size_t)e * HD;

  float acc[4][12];
  #pragma unroll
  for (int jm = 0; jm < 4; ++jm)
    #pragma unroll
    for (int jn = 0; jn < 12; ++jn) acc[jm][jn] = 0.f;

  __syncthreads();
  float gwr[4];
  #pragma unroll
  for (int jm = 0; jm < 4; ++jm) gwr[jm] = gws[w4 + jm];

  for (int c = 0; c < NCHUNK; ++c) {
    int i0 = c * KCH;
    float hb[4][2];
    #pragma unroll
    for (int jm = 0; jm < 4; ++jm) { hb[jm][0] = 0.f; hb[jm][1] = 0.f; }
    const float* p = w1e + i0 + lane;
    #pragma unroll 4
    for (int h = 0; h < HD; ++h) {
      ushort4 xu = *(const ushort4*)&x_t[h][w4];
      float wv0 = p[0];
      float wv1 = p[64];
      p += ID;
      float x0 = bf2f(xu.x), x1 = bf2f(xu.y), x2 = bf2f(xu.z), x3 = bf2f(xu.w);
      hb[0][0] += x0*wv0; hb[1][0] += x1*wv0; hb[2][0] += x2*wv0; hb[3][0] += x3*wv0;
      hb[0][1] += x0*wv1; hb[1][1] += x1*wv1; hb[2][1] += x2*wv1; hb[3][1] += x3*wv1;
    }
    float b1v0 = b1e[i0 + lane];
    float b1v1 = b1e[i0 + 64 + lane];
    __syncthreads();
    #pragma unroll
    for (int q = 0; q < 2; ++q) {
      int il = lane + 64*q;
      float bv = q ? b1v1 : b1v0;
      #pragma unroll
      for (int jm = 0; jm < 4; ++jm) {
        float v = hb[jm][q] + bv;
        v = 0.5f * v * (1.f + erff(v * 0.70710678118654752f));
        h_t[il][w4 + jm] = f2bf(v * gwr[jm]);
      }
    }
    __syncthreads();
    const float* q2 = w2e + (size_t)i0 * HD + lane;
    for (int k = 0; k < KCH; ++k) {
      ushort4 hu = *(const ushort4*)&h_t[k][w4];
      float h0 = bf2f(hu.x), h1 = bf2f(hu.y), h2 = bf2f(hu.z), h3 = bf2f(hu.w);
      #pragma unroll
      for (int jn = 0; jn < 12; ++jn) {
        float wv = q2[64*jn];
        acc[0][jn] += h0*wv; acc[1][jn] += h1*wv;
        acc[2][jn] += h2*wv; acc[3][jn] += h3*wv;
      }
      q2 += HD;
    }
  }

  #pragma unroll
  for (int jm = 0; jm < 4; ++jm) {
    int m = w4 + jm;
    int tk = toks[m];
    if (tk < 0) continue;
    float g = gwr[jm];
    float* orow = out + (size_t)tk * HD;
    #pragma unroll
    for (int jn = 0; jn < 12; ++jn) {
      int n = lane + 64*jn;
      atomicAdd(&orow[n], acc[jm][jn] + g * b2e[n]);
    }
  }
}

extern "C" void kernel_launch(void* const* d_in, const int* in_sizes, int n_in,
                              void* d_out, int out_size, void* d_ws, size_t ws_size,
                              hipStream_t stream)
{
  const float* x  = (const float*)d_in[0];
  const float* rw = (const float*)d_in[1];
  const float* rb = (const float*)d_in[2];
  const float* w1 = (const float*)d_in[3];
  const float* b1 = (const float*)d_in[4];
  const float* w2 = (const float*)d_in[5];
  const float* b2 = (const float*)d_in[6];

  float* out    = (float*)d_out;
  float* aux    = out + (size_t)NTOK * HD;
  float* gating = aux + 1;

  int*   W  = (int*)d_ws;
  float* Wf = (float*)d_ws;
  int*   offs   = W + 16;
  int*   tilesc = W + 32;
  int*   topi   = W + 64;
  float* topw   = Wf + 64 + NPAIR;
  int*   ptok   = W + 64 + 2*NPAIR;
  float* pwv    = Wf + 64 + 3*NPAIR;
  char*  wsB    = (char*)d_ws;
  const size_t OFF_XBF = 262400;
  const size_t OFF_W1T = OFF_XBF + (size_t)NTOK*HD*2;
  const size_t OFF_W2T = OFF_W1T + (size_t)NE*ID*HD*2;
  const size_t OFF_H   = OFF_W2T + (size_t)NE*ID*HD*2;      // 88342784
  const size_t NEED_FULL = OFF_H + (size_t)MAXTF*BMF*ID*2;  // ~195.3 MB

  u16* xbf = (u16*)(wsB + OFF_XBF);
  u16* w1t = (u16*)(wsB + OFF_W1T);
  u16* w2t = (u16*)(wsB + OFF_W2T);
  u16* hb  = (u16*)(wsB + OFF_H);

  bool fast = (ws_size >= NEED_FULL);

  hipMemsetAsync(d_out, 0, (size_t)NTOK * HD * sizeof(float), stream);

  if (fast) {
    prep_kernel<<<NTOK/4 + NW1T + NW2T, 256, 0, stream>>>(
        x, rw, rb, gating, topi, topw, xbf, w1, w1t, w2, w2t);
    plan_kernel<<<1, 1024, 0, stream>>>(topi, topw, offs, tilesc, ptok, pwv, BMF, aux);
    moe_gemm1_kernel<<<MAXTF * NY1, 256, 0, stream>>>(
        xbf, w1t, b1, offs, tilesc, ptok, pwv, hb);
    moe_gemm2_kernel<<<MAXTF * NY2, 256, 0, stream>>>(
        hb, w2t, b2, offs, tilesc, ptok, pwv, out);
  } else {
    router_kernel<<<NTOK/4, 256, 0, stream>>>(x, rw, rb, gating, topi, topw);
    plan_kernel<<<1, 1024, 0, stream>>>(topi, topw, offs, tilesc, ptok, pwv, BMS, aux);
    ffn_kernel<<<MAXTS, 512, 0, stream>>>(x, w1, b1, w2, b2, offs, tilesc, ptok, pwv, out);
  }
}